// Round 3
// baseline (141.086 us; speedup 1.0000x reference)
//
#include <hip/hip_runtime.h>

#define B_SZ 256
#define L_SZ 2048
#define T_SZ 32
#define START_IDX 0
#define STOP_IDX 1

// split config: 2 chains/wave (ILP-2), CLEN=64; 4 waves/block -> 8 chunks/block; tree 8->1
// 1024 blocks = 4 blocks/CU = 16 waves/CU; dual-chain fills MFMA->VALU latency within wave
#define CLEN 64
#define NPAIR 32          // CLEN/2
#define NSLOT 8
#define NMAT_SEQ 4        // block-matrices per sequence (block = 8*64 = 512 steps)
#define NBLK_TOT (B_SZ * NMAT_SEQ)   // 1024 blocks

// fallback (round-1) config
#define FB_NCH 16
#define FB_CLEN 128

// 6*ln2: fixed per-step 2^-6 scale folded into exp staging
#define SCALE_LN 4.1588830833596718565f

typedef __attribute__((ext_vector_type(8))) short bf16x8;
typedef __attribute__((ext_vector_type(4))) float f32x4;
typedef __attribute__((ext_vector_type(2))) float f32x2;

__device__ __forceinline__ unsigned fau(float f){ union{float f; unsigned u;} v; v.f=f; return v.u; }
__device__ __forceinline__ float uaf(unsigned u){ union{unsigned u; float f;} v; v.u=u; return v.f; }
__device__ __forceinline__ int pack_trunc(float lo, float hi){
  return (int)__builtin_amdgcn_perm(fau(hi), fau(lo), 0x07060302u);
}
__device__ __forceinline__ bf16x8 frag_of(const int* p){
  union{ int i[4]; bf16x8 v; } u;
  u.i[0]=p[0]; u.i[1]=p[1]; u.i[2]=p[2]; u.i[3]=p[3];
  return u.v;
}

// ---- 4x MFMA 16x16x32 bf16 (tree reduction use)
__device__ __forceinline__ void mfma4(bf16x8 A0, bf16x8 A1, bf16x8 B0, bf16x8 B1,
                                      f32x4& c00, f32x4& c01, f32x4& c10, f32x4& c11)
{
  const f32x4 z = {0.f,0.f,0.f,0.f};
  asm("s_nop 1\n\t"
      "v_mfma_f32_16x16x32_bf16 %0, %4, %5, %8\n\t"
      "v_mfma_f32_16x16x32_bf16 %1, %4, %6, %8\n\t"
      "v_mfma_f32_16x16x32_bf16 %2, %7, %5, %8\n\t"
      "v_mfma_f32_16x16x32_bf16 %3, %7, %6, %8\n\t"
      "s_nop 7\n\t"
      "s_nop 7"
      : "=&v"(c00), "=&v"(c01), "=&v"(c10), "=&v"(c11)
      : "v"(A0), "v"(B0), "v"(B1), "v"(A1), "v"(z));
}

// ---- 8x MFMA: two independent chains in one hazard region.
// A shared (constant transitions); Ba*/Bb* per-chain B frags.
// s_nop 1: VALU-write -> MFMA-read-A/B guard; s_nop 7 x2 after: MFMA-D -> VALU-read guard
// (last MFMA's D is the tightest; earlier ones have >=16cy slack already).
__device__ __forceinline__ void mfma8(bf16x8 A0, bf16x8 A1,
                                      bf16x8 Ba0, bf16x8 Ba1, bf16x8 Bb0, bf16x8 Bb1,
                                      f32x4& a00, f32x4& a01, f32x4& a10, f32x4& a11,
                                      f32x4& b00, f32x4& b01, f32x4& b10, f32x4& b11)
{
  const f32x4 z = {0.f,0.f,0.f,0.f};
  asm("s_nop 1\n\t"
      "v_mfma_f32_16x16x32_bf16 %0, %8, %10, %14\n\t"
      "v_mfma_f32_16x16x32_bf16 %1, %8, %11, %14\n\t"
      "v_mfma_f32_16x16x32_bf16 %2, %9, %10, %14\n\t"
      "v_mfma_f32_16x16x32_bf16 %3, %9, %11, %14\n\t"
      "v_mfma_f32_16x16x32_bf16 %4, %8, %12, %14\n\t"
      "v_mfma_f32_16x16x32_bf16 %5, %8, %13, %14\n\t"
      "v_mfma_f32_16x16x32_bf16 %6, %9, %12, %14\n\t"
      "v_mfma_f32_16x16x32_bf16 %7, %9, %13, %14\n\t"
      "s_nop 7\n\t"
      "s_nop 7"
      : "=&v"(a00), "=&v"(a01), "=&v"(a10), "=&v"(a11),
        "=&v"(b00), "=&v"(b01), "=&v"(b10), "=&v"(b11)
      : "v"(A0), "v"(A1), "v"(Ba0), "v"(Ba1), "v"(Bb0), "v"(Bb1), "v"(z));
}

__global__ void zero_kernel(float* out){ if(threadIdx.x==0) out[0]=0.f; }

// ---- 32x32 matrix product Q = compose(late, early) using standard frag layouts.
// L (early) in R-layout [origin*32+state], Rt (late) in T-layout [state*32+origin].
__device__ __forceinline__ int mat_prod(const unsigned short* L, const unsigned short* Rt,
                                        unsigned short* dst, bool writeT, int lane)
{
  const int g = lane >> 4, c16 = lane & 15;
  const int ko = 8*g;
  bf16x8 A0 = *(const bf16x8*)(L  + (c16*T_SZ      + ko));
  bf16x8 A1 = *(const bf16x8*)(L  + ((16+c16)*T_SZ + ko));
  bf16x8 B0 = *(const bf16x8*)(Rt + (c16*T_SZ      + ko));
  bf16x8 B1 = *(const bf16x8*)(Rt + ((16+c16)*T_SZ + ko));
  f32x4 q00,q01,q10,q11;
  mfma4(A0, A1, B0, B1, q00, q01, q10, q11);

  unsigned mb = (unsigned)__builtin_amdgcn_readfirstlane((int)fau(q00[0]));
  int e = (int)((mb>>23)&255u) - 127;
  float r = uaf((unsigned)(127-e)<<23);
  #pragma unroll
  for (int i=0;i<4;++i){ q00[i]*=r; q01[i]*=r; q10[i]*=r; q11[i]*=r; }

  if (!writeT){
    #pragma unroll
    for (int reg=0; reg<4; ++reg){
      int x0 = 4*g + reg, x1 = 16 + 4*g + reg;
      dst[x0*T_SZ + c16]      = (unsigned short)(fau(q00[reg])>>16);
      dst[x0*T_SZ + 16 + c16] = (unsigned short)(fau(q01[reg])>>16);
      dst[x1*T_SZ + c16]      = (unsigned short)(fau(q10[reg])>>16);
      dst[x1*T_SZ + 16 + c16] = (unsigned short)(fau(q11[reg])>>16);
    }
  } else {
    #pragma unroll
    for (int rp=0; rp<2; ++rp){
      int xb0 = 4*g + 2*rp, xb1 = 16 + 4*g + 2*rp;
      *(int*)&dst[c16*T_SZ + xb0]        = pack_trunc(q00[2*rp], q00[2*rp+1]);
      *(int*)&dst[(16+c16)*T_SZ + xb0]   = pack_trunc(q01[2*rp], q01[2*rp+1]);
      *(int*)&dst[c16*T_SZ + xb1]        = pack_trunc(q10[2*rp], q10[2*rp+1]);
      *(int*)&dst[(16+c16)*T_SZ + xb1]   = pack_trunc(q11[2*rp], q11[2*rp+1]);
    }
  }
  return e;
}

// ===================== kernel 1: dual-chain per wave + in-block 8->1 tree =====================
// block=256 (4 waves), each wave runs 2 independent 64-step chains (chunks 2w, 2w+1).
// launch_bounds(256,4): 4 waves/EU -> 4 blocks/CU resident; VGPR cap 128 for dual-chain state.
__global__ __launch_bounds__(256, 4) void crf_chunk_kernel(
    const float* __restrict__ efeats, const float* __restrict__ mask,
    const int* __restrict__ tgt, const float* __restrict__ trans,
    unsigned short* __restrict__ wsM, int* __restrict__ wsE,
    float* __restrict__ wsG, float* __restrict__ wsL,
    float* __restrict__ out)
{
  __shared__ float s_trans[T_SZ*T_SZ];
  __shared__ float s_d[4][256];                      // per-wave: 2 chains x 2 bufs x 64
  __shared__ unsigned short s_tree[NSLOT][T_SZ*T_SZ];// 16 KiB
  __shared__ int   s_et[NSLOT];
  __shared__ float s_gd[4], s_ml[4];

  const int tid  = threadIdx.x;
  const int w    = tid >> 6;
  const int lane = tid & 63;
  const int g    = lane >> 4;
  const int c16  = lane & 15;

  const int b  = blockIdx.x >> 2;        // 4 blocks per sequence
  const int q  = blockIdx.x & 3;
  const int l0A = q*(NSLOT*CLEN) + (2*w)*CLEN;   // chain A chunk start
  const int l0B = l0A + CLEN;                    // chain B chunk start

  // zero the output ahead of combine (stream order: all chunk blocks finish first)
  if (blockIdx.x == 0 && tid == 0) out[0] = 0.f;

  #pragma unroll
  for (int i=0;i<4;++i) s_trans[tid + i*256] = trans[tid + i*256];
  __syncthreads();

  // ---- constant A-frags (sigma-relabeled rows so C-layout == next B-layout lane-identically)
  bf16x8 A0f, A1f;
  {
    int a0i[4], a1i[4];
    #pragma unroll
    for (int I=0; I<2; ++I){
      int row = 8*(c16>>2) + 4*I + (c16&3);
      float e[8];
      #pragma unroll
      for (int j=0;j<8;++j) e[j] = __expf(s_trans[row*T_SZ + 8*g + j]);
      int* dst = I ? a1i : a0i;
      #pragma unroll
      for (int p=0;p<4;++p) dst[p] = pack_trunc(e[2*p], e[2*p+1]);
    }
    A0f = frag_of(a0i); A1f = frag_of(a1i);
  }

  // ---- B-frags = identity (both chains)
  int b0a[4], b1a[4], b0b[4], b1b[4];
  #pragma unroll
  for (int p=0;p<4;++p){
    int s0 = 8*g + 2*p, s1 = s0+1;
    unsigned lo = (s0==c16)?0x3f80u:0u, hi = (s1==c16)?0x3f80u:0u;
    b0a[p] = (int)(lo | (hi<<16));  b0b[p] = b0a[p];
    lo = (s0==16+c16)?0x3f80u:0u; hi = (s1==16+c16)?0x3f80u:0u;
    b1a[p] = (int)(lo | (hi<<16));  b1b[p] = b1a[p];
  }

  const long fbase = ((long)b * L_SZ) * T_SZ;
  const int  mbA = b*L_SZ + l0A;
  const int  mbB = b*L_SZ + l0B;

  // ---- per-lane per-step data: lane covers step (lane) of each chain
  float mA = mask[mbA + lane];
  float mB = mask[mbB + lane];
  int   tA = tgt [mbA + lane];
  int   tB = tgt [mbB + lane];
  int   tpA = (l0A + lane == 0) ? START_IDX : tgt[mbA + lane - 1];
  int   tpB = tgt[mbB + lane - 1];

  // gold + length, lane-parallel over both chains
  float emA = efeats[fbase + (long)(l0A+lane)*T_SZ + tA];
  float emB = efeats[fbase + (long)(l0B+lane)*T_SZ + tB];
  float gl = ((mA > 0.f) ? (s_trans[tA*T_SZ + tpA] + emA) : 0.f)
           + ((mB > 0.f) ? (s_trans[tB*T_SZ + tpB] + emB) : 0.f);
  float ml = mA + mB;
  #pragma unroll
  for (int off=32; off>0; off>>=1){ gl += __shfl_xor(gl, off, 64); ml += __shfl_xor(ml, off, 64); }

  unsigned long long mba = __ballot(mA > 0.f);
  unsigned long long mbb = __ballot(mB > 0.f);

  const float* fptA = efeats + fbase + (long)l0A*T_SZ;
  const float* fptB = efeats + fbase + (long)l0B*T_SZ;
  float* s_dwA = &s_d[w][0];
  float* s_dwB = &s_d[w][128];

  // prefetch pairs 1..4; stage pair 0 (both chains)
  float fqa[4], fqb[4];
  #pragma unroll
  for (int i=1; i<=4; ++i){ fqa[i&3] = fptA[i*64 + lane]; fqb[i&3] = fptB[i*64 + lane]; }
  s_dwA[lane] = __expf(fptA[lane] - SCALE_LN);
  s_dwB[lane] = __expf(fptB[lane] - SCALE_LN);

  if ((mba & mbb) == ~0ull){
    // ================= HOT: dense mask, branchless, dual-chain =================
    #pragma unroll 2
    for (int p=0; p<NPAIR; ++p){
      s_dwA[((p+1)&1)*64 + lane] = __expf(fqa[(p+1)&3] - SCALE_LN);
      s_dwB[((p+1)&1)*64 + lane] = __expf(fqb[(p+1)&3] - SCALE_LN);
      int np = p+5; np = (np > NPAIR-1) ? (NPAIR-1) : np;
      fqa[(p+1)&3] = fptA[np*64 + lane];
      fqb[(p+1)&3] = fptB[np*64 + lane];
      const float* dbA = &s_dwA[(p&1)*64];
      const float* dbB = &s_dwB[(p&1)*64];
      #pragma unroll
      for (int h=0; h<2; ++h){
        f32x4 cA00,cA01,cA10,cA11, cB00,cB01,cB10,cB11;
        mfma8(A0f, A1f, frag_of(b0a), frag_of(b1a), frag_of(b0b), frag_of(b1b),
              cA00,cA01,cA10,cA11, cB00,cB01,cB10,cB11);

        const float4* dvA = (const float4*)(dbA + h*32);
        const float4* dvB = (const float4*)(dbB + h*32);
        float4 dlA = dvA[2*g], dhA = dvA[2*g+1];
        float4 dlB = dvB[2*g], dhB = dvB[2*g+1];

        { // chain A scale+pack
          f32x2 q0={cA00[0],cA00[1]}; q0 *= (f32x2){dlA.x,dlA.y};
          f32x2 q1={cA00[2],cA00[3]}; q1 *= (f32x2){dlA.z,dlA.w};
          f32x2 q2={cA01[0],cA01[1]}; q2 *= (f32x2){dlA.x,dlA.y};
          f32x2 q3={cA01[2],cA01[3]}; q3 *= (f32x2){dlA.z,dlA.w};
          f32x2 q4={cA10[0],cA10[1]}; q4 *= (f32x2){dhA.x,dhA.y};
          f32x2 q5={cA10[2],cA10[3]}; q5 *= (f32x2){dhA.z,dhA.w};
          f32x2 q6={cA11[0],cA11[1]}; q6 *= (f32x2){dhA.x,dhA.y};
          f32x2 q7={cA11[2],cA11[3]}; q7 *= (f32x2){dhA.z,dhA.w};
          b0a[0]=pack_trunc(q0[0],q0[1]); b0a[1]=pack_trunc(q1[0],q1[1]);
          b0a[2]=pack_trunc(q4[0],q4[1]); b0a[3]=pack_trunc(q5[0],q5[1]);
          b1a[0]=pack_trunc(q2[0],q2[1]); b1a[1]=pack_trunc(q3[0],q3[1]);
          b1a[2]=pack_trunc(q6[0],q6[1]); b1a[3]=pack_trunc(q7[0],q7[1]);
        }
        { // chain B scale+pack
          f32x2 q0={cB00[0],cB00[1]}; q0 *= (f32x2){dlB.x,dlB.y};
          f32x2 q1={cB00[2],cB00[3]}; q1 *= (f32x2){dlB.z,dlB.w};
          f32x2 q2={cB01[0],cB01[1]}; q2 *= (f32x2){dlB.x,dlB.y};
          f32x2 q3={cB01[2],cB01[3]}; q3 *= (f32x2){dlB.z,dlB.w};
          f32x2 q4={cB10[0],cB10[1]}; q4 *= (f32x2){dhB.x,dhB.y};
          f32x2 q5={cB10[2],cB10[3]}; q5 *= (f32x2){dhB.z,dhB.w};
          f32x2 q6={cB11[0],cB11[1]}; q6 *= (f32x2){dhB.x,dhB.y};
          f32x2 q7={cB11[2],cB11[3]}; q7 *= (f32x2){dhB.z,dhB.w};
          b0b[0]=pack_trunc(q0[0],q0[1]); b0b[1]=pack_trunc(q1[0],q1[1]);
          b0b[2]=pack_trunc(q4[0],q4[1]); b0b[3]=pack_trunc(q5[0],q5[1]);
          b1b[0]=pack_trunc(q2[0],q2[1]); b1b[1]=pack_trunc(q3[0],q3[1]);
          b1b[2]=pack_trunc(q6[0],q6[1]); b1b[3]=pack_trunc(q7[0],q7[1]);
        }
      }
    }
  } else {
    // ================= COLD: arbitrary mask (compute both, commit per-chain) =================
    for (int p=0; p<NPAIR; ++p){
      s_dwA[((p+1)&1)*64 + lane] = __expf(fqa[(p+1)&3] - SCALE_LN);
      s_dwB[((p+1)&1)*64 + lane] = __expf(fqb[(p+1)&3] - SCALE_LN);
      int np = p+5; if (np > NPAIR-1) np = NPAIR-1;
      fqa[(p+1)&3] = fptA[np*64 + lane];
      fqb[(p+1)&3] = fptB[np*64 + lane];
      const float* dbA = &s_dwA[(p&1)*64];
      const float* dbB = &s_dwB[(p&1)*64];
      #pragma unroll
      for (int h=0; h<2; ++h){
        int t = 2*p + h;
        f32x4 cA00,cA01,cA10,cA11, cB00,cB01,cB10,cB11;
        mfma8(A0f, A1f, frag_of(b0a), frag_of(b1a), frag_of(b0b), frag_of(b1b),
              cA00,cA01,cA10,cA11, cB00,cB01,cB10,cB11);

        if ((mba >> t) & 1ull){  // wave-uniform
          const float4* dvA = (const float4*)(dbA + h*32);
          float4 dl = dvA[2*g], dh2 = dvA[2*g+1];
          float f0=dl.x, f1=dl.y, f2=dl.z, f3=dl.w;
          float f4=dh2.x, f5=dh2.y, f6=dh2.z, f7=dh2.w;
          cA00[0]*=f0; cA00[1]*=f1; cA00[2]*=f2; cA00[3]*=f3;
          cA01[0]*=f0; cA01[1]*=f1; cA01[2]*=f2; cA01[3]*=f3;
          cA10[0]*=f4; cA10[1]*=f5; cA10[2]*=f6; cA10[3]*=f7;
          cA11[0]*=f4; cA11[1]*=f5; cA11[2]*=f6; cA11[3]*=f7;
          b0a[0]=pack_trunc(cA00[0],cA00[1]); b0a[1]=pack_trunc(cA00[2],cA00[3]);
          b0a[2]=pack_trunc(cA10[0],cA10[1]); b0a[3]=pack_trunc(cA10[2],cA10[3]);
          b1a[0]=pack_trunc(cA01[0],cA01[1]); b1a[1]=pack_trunc(cA01[2],cA01[3]);
          b1a[2]=pack_trunc(cA11[0],cA11[1]); b1a[3]=pack_trunc(cA11[2],cA11[3]);
        }
        if ((mbb >> t) & 1ull){  // wave-uniform
          const float4* dvB = (const float4*)(dbB + h*32);
          float4 dl = dvB[2*g], dh2 = dvB[2*g+1];
          float f0=dl.x, f1=dl.y, f2=dl.z, f3=dl.w;
          float f4=dh2.x, f5=dh2.y, f6=dh2.z, f7=dh2.w;
          cB00[0]*=f0; cB00[1]*=f1; cB00[2]*=f2; cB00[3]*=f3;
          cB01[0]*=f0; cB01[1]*=f1; cB01[2]*=f2; cB01[3]*=f3;
          cB10[0]*=f4; cB10[1]*=f5; cB10[2]*=f6; cB10[3]*=f7;
          cB11[0]*=f4; cB11[1]*=f5; cB11[2]*=f6; cB11[3]*=f7;
          b0b[0]=pack_trunc(cB00[0],cB00[1]); b0b[1]=pack_trunc(cB00[2],cB00[3]);
          b0b[2]=pack_trunc(cB10[0],cB10[1]); b0b[3]=pack_trunc(cB10[2],cB10[3]);
          b1b[0]=pack_trunc(cB01[0],cB01[1]); b1b[1]=pack_trunc(cB01[2],cB01[3]);
          b1b[2]=pack_trunc(cB11[0],cB11[1]); b1b[3]=pack_trunc(cB11[2],cB11[3]);
        }
      }
    }
  }

  // ---- write chunk matrices to tree slots (chain A -> slot 2w in R layout, chain B -> slot 2w+1 in T layout)
  {
    unsigned short* S = &s_tree[2*w][0];
    #pragma unroll
    for (int p=0;p<4;++p){
      int s = 8*g + 2*p;
      *(int*)&S[c16*T_SZ + s]      = b0a[p];
      *(int*)&S[(16+c16)*T_SZ + s] = b1a[p];
    }
    unsigned short* St = &s_tree[2*w+1][0];
    #pragma unroll
    for (int p=0;p<4;++p){
      int s = 8*g + 2*p;
      St[s*T_SZ + c16]          = (unsigned short)(b0b[p] & 0xffff);
      St[(s+1)*T_SZ + c16]      = (unsigned short)(((unsigned)b0b[p])>>16);
      St[s*T_SZ + 16 + c16]     = (unsigned short)(b1b[p] & 0xffff);
      St[(s+1)*T_SZ + 16 + c16] = (unsigned short)(((unsigned)b1b[p])>>16);
    }
  }
  if (lane==0){
    s_et[2*w]   = 6 * __popcll(mba);
    s_et[2*w+1] = 6 * __popcll(mbb);
    s_gd[w] = gl; s_ml[w] = ml;
  }
  __syncthreads();

  // ---- tree: 8 -> 1 (4 waves at level 1)
  {
    int e = mat_prod(&s_tree[2*w][0], &s_tree[2*w+1][0], &s_tree[2*w][0], (w&1)!=0, lane);
    if (lane==0) s_et[2*w] = s_et[2*w] + s_et[2*w+1] + e;
  }
  __syncthreads();
  if (w < 2){
    int e = mat_prod(&s_tree[4*w][0], &s_tree[4*w+2][0], &s_tree[4*w][0], (w&1)!=0, lane);
    if (lane==0) s_et[4*w] = s_et[4*w] + s_et[4*w+2] + e;
  }
  __syncthreads();
  if (w == 0){
    int e = mat_prod(&s_tree[0][0], &s_tree[4][0], &s_tree[0][0], false, lane);
    if (lane==0) s_et[0] = s_et[0] + s_et[4] + e;
  }
  __syncthreads();

  // ---- export block matrix (R layout) + scalars
  const int bid = blockIdx.x;
  ((int*)(wsM + (long)bid*(T_SZ*T_SZ)))[tid]       = ((const int*)&s_tree[0][0])[tid];
  ((int*)(wsM + (long)bid*(T_SZ*T_SZ)))[tid + 256] = ((const int*)&s_tree[0][0])[tid + 256];
  if (tid == 0){
    wsE[bid] = s_et[0];
    float gs=0.f, ls=0.f;
    #pragma unroll
    for (int i=0;i<4;++i){ gs += s_gd[i]; ls += s_ml[i]; }
    wsG[bid] = gs; wsL[bid] = ls;
  }
}

// ===================== kernel 2: combine 4 block-matrices per sequence =====================
__global__ __launch_bounds__(64) void crf_combine_kernel(
    const unsigned short* __restrict__ wsM, const int* __restrict__ wsE,
    const float* __restrict__ wsG, const float* __restrict__ wsL,
    const int* __restrict__ tgt, const float* __restrict__ trans,
    float* __restrict__ out)
{
  __shared__ unsigned short sM[NMAT_SEQ*T_SZ*T_SZ];   // 8 KiB = NMAT_SEQ*128 uint4
  __shared__ float s_v[T_SZ];

  const int tid = threadIdx.x;
  const int b   = blockIdx.x;

  const uint4* src = (const uint4*)(wsM + (long)b*NMAT_SEQ*T_SZ*T_SZ);
  #pragma unroll
  for (int i=0;i<NMAT_SEQ*2;++i) ((uint4*)sM)[tid + i*64] = src[tid + i*64];
  __syncthreads();

  const int s = tid & 31;
  float v = (s==START_IDX)?1.f:0.f;
  int E = 0;
  #pragma unroll
  for (int j=0; j<NMAT_SEQ; ++j){
    if (tid < 32) s_v[s] = v;
    __syncthreads();
    const unsigned short* M = &sM[j*T_SZ*T_SZ];
    float u = 0.f;
    #pragma unroll 8
    for (int x=0; x<T_SZ; ++x){
      float mv = uaf(((unsigned)M[x*T_SZ + s])<<16);
      u = fmaf(mv, s_v[x], u);
    }
    unsigned ub = (unsigned)__builtin_amdgcn_readfirstlane((int)fau(u));
    int eu = (int)((ub>>23)&255u)-127;
    E += wsE[b*NMAT_SEQ + j] + eu;
    v = u * uaf((unsigned)(127-eu)<<23);
    __syncthreads();
  }
  float term = v * __expf(trans[STOP_IDX*T_SZ + s]);
  #pragma unroll
  for (int off=16; off>0; off>>=1) term += __shfl_xor(term, off, 32);
  float fwd = (float)E * 0.69314718055994530942f + __logf(term);

  if (tid == 0){
    float gp = 0.f, lp = 0.f;
    #pragma unroll
    for (int j=0;j<NMAT_SEQ;++j){ gp += wsG[b*NMAT_SEQ+j]; lp += wsL[b*NMAT_SEQ+j]; }
    int len = (int)lp;
    int last_tag = (len==0)? START_IDX : tgt[b*L_SZ + len-1];
    float goldT = gp + trans[STOP_IDX*T_SZ + last_tag];
    atomicAdd(out, (fwd - goldT) * (1.0f/B_SZ));
  }
}

// ===================== fallback: round-1 single kernel (no workspace) =====================
__global__ __launch_bounds__(1024) void crf_loss_kernel(
    const float* __restrict__ efeats, const float* __restrict__ mask,
    const int* __restrict__ tgt, const float* __restrict__ trans,
    float* __restrict__ out)
{
  __shared__ float s_trans[T_SZ*T_SZ];
  __shared__ float s_d[FB_NCH][T_SZ];
  __shared__ unsigned short s_M[FB_NCH][T_SZ*T_SZ];
  __shared__ int   s_es[FB_NCH];
  __shared__ float s_gd[FB_NCH];
  __shared__ float s_mlv[FB_NCH];

  const int tid  = threadIdx.x;
  const int b    = blockIdx.x;
  const int w    = tid >> 6;
  const int lane = tid & 63;
  const int g    = lane >> 4;
  const int c16  = lane & 15;
  const int i32  = lane & 31;

  s_trans[tid] = trans[tid];
  __syncthreads();

  int a0[4], a1[4];
  #pragma unroll
  for (int I=0; I<2; ++I){
    int row = 8*(c16>>2) + 4*I + (c16&3);
    float e[8];
    #pragma unroll
    for (int j=0;j<8;++j) e[j] = __expf(s_trans[row*T_SZ + 8*g + j]);
    int* dst = I ? a1 : a0;
    #pragma unroll
    for (int p=0;p<4;++p) dst[p] = pack_trunc(e[2*p], e[2*p+1]);
  }

  int b0[4], b1[4];
  #pragma unroll
  for (int p=0;p<4;++p){
    int s0 = 8*g + 2*p, s1 = s0+1;
    unsigned lo = (s0==c16)?0x3f80u:0u, hi = (s1==c16)?0x3f80u:0u;
    b0[p] = (int)(lo | (hi<<16));
    lo = (s0==16+c16)?0x3f80u:0u; hi = (s1==16+c16)?0x3f80u:0u;
    b1[p] = (int)(lo | (hi<<16));
  }

  const int l0 = w * FB_CLEN;
  const long fbase = ((long)b * L_SZ) * T_SZ;

  float fqv[4];
  #pragma unroll
  for (int i=0;i<4;++i) fqv[i] = efeats[fbase + (long)(l0+i)*T_SZ + i32];

  int   tA = tgt [b*L_SZ + l0 + lane];
  int   tB = tgt [b*L_SZ + l0 + 64 + lane];
  float mA = mask[b*L_SZ + l0 + lane];
  float mB = mask[b*L_SZ + l0 + 64 + lane];
  int prev = (l0==0) ? START_IDX : tgt[b*L_SZ + l0 - 1];

  int esum = 0;
  float gold = 0.f, mlen = 0.f;
  const f32x4 zf = {0.f,0.f,0.f,0.f};

  #pragma unroll 4
  for (int t=0; t<FB_CLEN; ++t){
    float fcur = fqv[t&3];
    int lpf = l0 + t + 4; lpf = (lpf < L_SZ) ? lpf : (L_SZ-1);
    fqv[t&3] = efeats[fbase + (long)lpf*T_SZ + i32];

    float mk  = uaf((unsigned)__builtin_amdgcn_readlane((int)fau((t<64)?mA:mB), t&63));
    int   cur = __builtin_amdgcn_readlane((t<64)?tA:tB, t&63);
    mlen += mk;

    if (mk > 0.f){
      if (lane < 32) s_d[w][lane] = __expf(fcur);

      f32x4 c00 = __builtin_amdgcn_mfma_f32_16x16x32_bf16(frag_of(a0), frag_of(b0), zf, 0,0,0);
      f32x4 c01 = __builtin_amdgcn_mfma_f32_16x16x32_bf16(frag_of(a0), frag_of(b1), zf, 0,0,0);
      f32x4 c10 = __builtin_amdgcn_mfma_f32_16x16x32_bf16(frag_of(a1), frag_of(b0), zf, 0,0,0);
      f32x4 c11 = __builtin_amdgcn_mfma_f32_16x16x32_bf16(frag_of(a1), frag_of(b1), zf, 0,0,0);

      const float4* dv = (const float4*)(&s_d[w][0]);
      float4 dl = dv[2*g], dh = dv[2*g+1];
      float f0=dl.x, f1=dl.y, f2=dl.z, f3=dl.w;
      float f4=dh.x, f5=dh.y, f6=dh.z, f7=dh.w;

      float m00 = c00[0]*f0;
      unsigned mb = (unsigned)__builtin_amdgcn_readfirstlane((int)fau(m00));
      int e = (int)((mb>>23)&255u) - 127;
      esum += e;
      float r = uaf((unsigned)(127-e)<<23);
      f0*=r; f1*=r; f2*=r; f3*=r; f4*=r; f5*=r; f6*=r; f7*=r;

      c00[0]*=f0; c00[1]*=f1; c00[2]*=f2; c00[3]*=f3;
      c01[0]*=f0; c01[1]*=f1; c01[2]*=f2; c01[3]*=f3;
      c10[0]*=f4; c10[1]*=f5; c10[2]*=f6; c10[3]*=f7;
      c11[0]*=f4; c11[1]*=f5; c11[2]*=f6; c11[3]*=f7;

      b0[0]=pack_trunc(c00[0],c00[1]); b0[1]=pack_trunc(c00[2],c00[3]);
      b0[2]=pack_trunc(c10[0],c10[1]); b0[3]=pack_trunc(c10[2],c10[3]);
      b1[0]=pack_trunc(c01[0],c01[1]); b1[1]=pack_trunc(c01[2],c01[3]);
      b1[2]=pack_trunc(c11[0],c11[1]); b1[3]=pack_trunc(c11[2],c11[3]);

      float tp   = s_trans[cur*T_SZ + prev];
      float emit = uaf((unsigned)__builtin_amdgcn_readlane((int)fau(fcur), cur));
      gold += tp + emit;
    }
    prev = cur;
  }

  #pragma unroll
  for (int p=0;p<4;++p){
    int s = 8*g + 2*p;
    *(int*)((char*)(&s_M[w][0]) + (((long)(c16   )*T_SZ + s) * 2)) = b0[p];
    *(int*)((char*)(&s_M[w][0]) + (((long)(16+c16)*T_SZ + s) * 2)) = b1[p];
  }
  if (lane==0){ s_es[w]=esum; s_gd[w]=gold; s_mlv[w]=mlen; }
  __syncthreads();

  if (w==0){
    int s = i32;
    float v = (s==START_IDX)?1.f:0.f;
    int E = 0;
    for (int c=0;c<FB_NCH;++c){
      float u=0.f;
      #pragma unroll 8
      for (int k=0;k<T_SZ;++k){
        float mv = uaf(((unsigned)s_M[c][k*T_SZ + s])<<16);
        float vk = uaf((unsigned)__builtin_amdgcn_readlane((int)fau(v), k));
        u = fmaf(mv, vk, u);
      }
      unsigned ub = (unsigned)__builtin_amdgcn_readfirstlane((int)fau(u));
      int eu = (int)((ub>>23)&255u)-127;
      E += s_es[c] + eu;
      v = u * uaf((unsigned)(127-eu)<<23);
    }
    float term = v * __expf(s_trans[STOP_IDX*T_SZ + s]);
    #pragma unroll
    for (int off=16; off>0; off>>=1) term += __shfl_xor(term, off, 32);
    float fwd = (float)E * 0.69314718055994530942f + __logf(term);

    float gp = (s<FB_NCH)? s_gd[s] : 0.f;
    float lp = (s<FB_NCH)? s_mlv[s] : 0.f;
    #pragma unroll
    for (int off=16; off>0; off>>=1){ gp += __shfl_xor(gp, off, 32); lp += __shfl_xor(lp, off, 32); }
    int len = (int)lp;
    int last_tag = (len==0)? START_IDX : tgt[b*L_SZ + (len-1)];
    float goldT = gp + s_trans[STOP_IDX*T_SZ + last_tag];
    if (tid==0) atomicAdd(out, (fwd - goldT) * (1.0f/B_SZ));
  }
}

extern "C" void kernel_launch(void* const* d_in, const int* in_sizes, int n_in,
                              void* d_out, int out_size, void* d_ws, size_t ws_size,
                              hipStream_t stream)
{
  const float* efeats = (const float*)d_in[0];
  const float* mask   = (const float*)d_in[1];
  const int*   tgt    = (const int*)d_in[2];
  const float* trans  = (const float*)d_in[3];
  float* out = (float*)d_out;

  const size_t needM = (size_t)NBLK_TOT * T_SZ * T_SZ * 2;   // 2 MiB
  const size_t need  = needM + (size_t)NBLK_TOT * 12;

  if (ws_size >= need){
    unsigned short* wsM = (unsigned short*)d_ws;
    char* p = (char*)d_ws + needM;
    int*   wsE = (int*)p;
    float* wsG = (float*)(p + (size_t)NBLK_TOT*4);
    float* wsL = (float*)(p + (size_t)NBLK_TOT*8);
    crf_chunk_kernel<<<dim3(NBLK_TOT), dim3(256), 0, stream>>>(
        efeats, mask, tgt, trans, wsM, wsE, wsG, wsL, out);
    crf_combine_kernel<<<dim3(B_SZ), dim3(64), 0, stream>>>(
        wsM, wsE, wsG, wsL, tgt, trans, out);
  } else {
    zero_kernel<<<dim3(1), dim3(64), 0, stream>>>(out);
    crf_loss_kernel<<<dim3(B_SZ), dim3(1024), 0, stream>>>(efeats, mask, tgt, trans, out);
  }
}

// Round 4
// 139.124 us; speedup vs baseline: 1.0141x; 1.0141x over previous
//
#include <hip/hip_runtime.h>

#define B_SZ 256
#define L_SZ 2048
#define T_SZ 32
#define START_IDX 0
#define STOP_IDX 1

// split config: 2 chains/wave STAGGERED (A one step ahead of B), CLEN=64;
// 4 waves/block -> 8 chunks/block; tree 8->1; 1024 blocks = 4 blocks/CU.
// Stagger: each MFMA's latency is covered by the OTHER chain's pack-VALU;
// schedule pinned with sched_barrier(0) into 8 regions per pair.
#define CLEN 64
#define NPAIR 32          // CLEN/2
#define NSLOT 8
#define NMAT_SEQ 4        // block-matrices per sequence (block = 8*64 = 512 steps)
#define NBLK_TOT (B_SZ * NMAT_SEQ)   // 1024 blocks

// fallback (round-1) config
#define FB_NCH 16
#define FB_CLEN 128

// 6*ln2: fixed per-step 2^-6 scale folded into exp staging
#define SCALE_LN 4.1588830833596718565f

typedef __attribute__((ext_vector_type(8))) short bf16x8;
typedef __attribute__((ext_vector_type(4))) float f32x4;
typedef __attribute__((ext_vector_type(2))) float f32x2;

__device__ __forceinline__ unsigned fau(float f){ union{float f; unsigned u;} v; v.f=f; return v.u; }
__device__ __forceinline__ float uaf(unsigned u){ union{unsigned u; float f;} v; v.u=u; return v.f; }
__device__ __forceinline__ int pack_trunc(float lo, float hi){
  return (int)__builtin_amdgcn_perm(fau(hi), fau(lo), 0x07060302u);
}
__device__ __forceinline__ bf16x8 frag_of(const int* p){
  union{ int i[4]; bf16x8 v; } u;
  u.i[0]=p[0]; u.i[1]=p[1]; u.i[2]=p[2]; u.i[3]=p[3];
  return u.v;
}

// scale C quadrants by d and pack to bf16 B-frags (r3-verified mapping)
#define PACKQ(c00,c01,c10,c11, dl,dh2, o0,o1) do{ \
  f32x2 q0={c00[0],c00[1]}; q0 *= (f32x2){dl.x,dl.y};   \
  f32x2 q1={c00[2],c00[3]}; q1 *= (f32x2){dl.z,dl.w};   \
  f32x2 q2={c01[0],c01[1]}; q2 *= (f32x2){dl.x,dl.y};   \
  f32x2 q3={c01[2],c01[3]}; q3 *= (f32x2){dl.z,dl.w};   \
  f32x2 q4={c10[0],c10[1]}; q4 *= (f32x2){dh2.x,dh2.y}; \
  f32x2 q5={c10[2],c10[3]}; q5 *= (f32x2){dh2.z,dh2.w}; \
  f32x2 q6={c11[0],c11[1]}; q6 *= (f32x2){dh2.x,dh2.y}; \
  f32x2 q7={c11[2],c11[3]}; q7 *= (f32x2){dh2.z,dh2.w}; \
  o0[0]=pack_trunc(q0[0],q0[1]); o0[1]=pack_trunc(q1[0],q1[1]); \
  o0[2]=pack_trunc(q4[0],q4[1]); o0[3]=pack_trunc(q5[0],q5[1]); \
  o1[0]=pack_trunc(q2[0],q2[1]); o1[1]=pack_trunc(q3[0],q3[1]); \
  o1[2]=pack_trunc(q6[0],q6[1]); o1[3]=pack_trunc(q7[0],q7[1]); \
}while(0)

// ---- 4x MFMA, guarded (prologue + tree use): s_nop 7 x2 covers MFMA-D -> VALU-read
__device__ __forceinline__ void mfma4(bf16x8 A0, bf16x8 A1, bf16x8 B0, bf16x8 B1,
                                      f32x4& c00, f32x4& c01, f32x4& c10, f32x4& c11)
{
  const f32x4 z = {0.f,0.f,0.f,0.f};
  asm("s_nop 1\n\t"
      "v_mfma_f32_16x16x32_bf16 %0, %4, %5, %8\n\t"
      "v_mfma_f32_16x16x32_bf16 %1, %4, %6, %8\n\t"
      "v_mfma_f32_16x16x32_bf16 %2, %7, %5, %8\n\t"
      "v_mfma_f32_16x16x32_bf16 %3, %7, %6, %8\n\t"
      "s_nop 7\n\t"
      "s_nop 7"
      : "=&v"(c00), "=&v"(c01), "=&v"(c10), "=&v"(c11)
      : "v"(A0), "v"(B0), "v"(B1), "v"(A1), "v"(z));
}

// ---- 4x MFMA, lean (staggered loop): MFMA-D -> VALU-read distance guaranteed
// by the pinned schedule (>=25 instructions); only VALU->MFMA s_nop 1 kept.
__device__ __forceinline__ void mfma4v(bf16x8 A0, bf16x8 A1, bf16x8 B0, bf16x8 B1,
                                       f32x4& c00, f32x4& c01, f32x4& c10, f32x4& c11)
{
  const f32x4 z = {0.f,0.f,0.f,0.f};
  asm volatile(
      "s_nop 1\n\t"
      "v_mfma_f32_16x16x32_bf16 %0, %4, %5, %8\n\t"
      "v_mfma_f32_16x16x32_bf16 %1, %4, %6, %8\n\t"
      "v_mfma_f32_16x16x32_bf16 %2, %7, %5, %8\n\t"
      "v_mfma_f32_16x16x32_bf16 %3, %7, %6, %8"
      : "=&v"(c00), "=&v"(c01), "=&v"(c10), "=&v"(c11)
      : "v"(A0), "v"(B0), "v"(B1), "v"(A1), "v"(z));
}

// ---- 8x MFMA batched (cold path only)
__device__ __forceinline__ void mfma8(bf16x8 A0, bf16x8 A1,
                                      bf16x8 Ba0, bf16x8 Ba1, bf16x8 Bb0, bf16x8 Bb1,
                                      f32x4& a00, f32x4& a01, f32x4& a10, f32x4& a11,
                                      f32x4& b00, f32x4& b01, f32x4& b10, f32x4& b11)
{
  const f32x4 z = {0.f,0.f,0.f,0.f};
  asm("s_nop 1\n\t"
      "v_mfma_f32_16x16x32_bf16 %0, %8, %10, %14\n\t"
      "v_mfma_f32_16x16x32_bf16 %1, %8, %11, %14\n\t"
      "v_mfma_f32_16x16x32_bf16 %2, %9, %10, %14\n\t"
      "v_mfma_f32_16x16x32_bf16 %3, %9, %11, %14\n\t"
      "v_mfma_f32_16x16x32_bf16 %4, %8, %12, %14\n\t"
      "v_mfma_f32_16x16x32_bf16 %5, %8, %13, %14\n\t"
      "v_mfma_f32_16x16x32_bf16 %6, %9, %12, %14\n\t"
      "v_mfma_f32_16x16x32_bf16 %7, %9, %13, %14\n\t"
      "s_nop 7\n\t"
      "s_nop 7"
      : "=&v"(a00), "=&v"(a01), "=&v"(a10), "=&v"(a11),
        "=&v"(b00), "=&v"(b01), "=&v"(b10), "=&v"(b11)
      : "v"(A0), "v"(A1), "v"(Ba0), "v"(Ba1), "v"(Bb0), "v"(Bb1), "v"(z));
}

__global__ void zero_kernel(float* out){ if(threadIdx.x==0) out[0]=0.f; }

// ---- 32x32 matrix product Q = compose(late, early) using standard frag layouts.
__device__ __forceinline__ int mat_prod(const unsigned short* L, const unsigned short* Rt,
                                        unsigned short* dst, bool writeT, int lane)
{
  const int g = lane >> 4, c16 = lane & 15;
  const int ko = 8*g;
  bf16x8 A0 = *(const bf16x8*)(L  + (c16*T_SZ      + ko));
  bf16x8 A1 = *(const bf16x8*)(L  + ((16+c16)*T_SZ + ko));
  bf16x8 B0 = *(const bf16x8*)(Rt + (c16*T_SZ      + ko));
  bf16x8 B1 = *(const bf16x8*)(Rt + ((16+c16)*T_SZ + ko));
  f32x4 q00,q01,q10,q11;
  mfma4(A0, A1, B0, B1, q00, q01, q10, q11);

  unsigned mb = (unsigned)__builtin_amdgcn_readfirstlane((int)fau(q00[0]));
  int e = (int)((mb>>23)&255u) - 127;
  float r = uaf((unsigned)(127-e)<<23);
  #pragma unroll
  for (int i=0;i<4;++i){ q00[i]*=r; q01[i]*=r; q10[i]*=r; q11[i]*=r; }

  if (!writeT){
    #pragma unroll
    for (int reg=0; reg<4; ++reg){
      int x0 = 4*g + reg, x1 = 16 + 4*g + reg;
      dst[x0*T_SZ + c16]      = (unsigned short)(fau(q00[reg])>>16);
      dst[x0*T_SZ + 16 + c16] = (unsigned short)(fau(q01[reg])>>16);
      dst[x1*T_SZ + c16]      = (unsigned short)(fau(q10[reg])>>16);
      dst[x1*T_SZ + 16 + c16] = (unsigned short)(fau(q11[reg])>>16);
    }
  } else {
    #pragma unroll
    for (int rp=0; rp<2; ++rp){
      int xb0 = 4*g + 2*rp, xb1 = 16 + 4*g + 2*rp;
      *(int*)&dst[c16*T_SZ + xb0]        = pack_trunc(q00[2*rp], q00[2*rp+1]);
      *(int*)&dst[(16+c16)*T_SZ + xb0]   = pack_trunc(q01[2*rp], q01[2*rp+1]);
      *(int*)&dst[c16*T_SZ + xb1]        = pack_trunc(q10[2*rp], q10[2*rp+1]);
      *(int*)&dst[(16+c16)*T_SZ + xb1]   = pack_trunc(q11[2*rp], q11[2*rp+1]);
    }
  }
  return e;
}

// ===================== kernel 1: staggered dual-chain + in-block 8->1 tree =====================
__global__ __launch_bounds__(256, 4) void crf_chunk_kernel(
    const float* __restrict__ efeats, const float* __restrict__ mask,
    const int* __restrict__ tgt, const float* __restrict__ trans,
    unsigned short* __restrict__ wsM, int* __restrict__ wsE,
    float* __restrict__ wsG, float* __restrict__ wsL,
    float* __restrict__ out)
{
  __shared__ float s_trans[T_SZ*T_SZ];
  __shared__ float s_d[4][256];                      // per-wave: 2 chains x 2 bufs x 64
  __shared__ unsigned short s_tree[NSLOT][T_SZ*T_SZ];// 16 KiB
  __shared__ int   s_et[NSLOT];
  __shared__ float s_gd[4], s_ml[4];

  const int tid  = threadIdx.x;
  const int w    = tid >> 6;
  const int lane = tid & 63;
  const int g    = lane >> 4;
  const int c16  = lane & 15;
  const int gq   = 2*g;

  const int b  = blockIdx.x >> 2;        // 4 blocks per sequence
  const int q  = blockIdx.x & 3;
  const int l0A = q*(NSLOT*CLEN) + (2*w)*CLEN;   // chain A chunk start
  const int l0B = l0A + CLEN;                    // chain B chunk start

  if (blockIdx.x == 0 && tid == 0) out[0] = 0.f;

  #pragma unroll
  for (int i=0;i<4;++i) s_trans[tid + i*256] = trans[tid + i*256];
  __syncthreads();

  // ---- constant A-frags (sigma-relabeled rows so C-layout == next B-layout lane-identically)
  bf16x8 A0f, A1f;
  {
    int a0i[4], a1i[4];
    #pragma unroll
    for (int I=0; I<2; ++I){
      int row = 8*(c16>>2) + 4*I + (c16&3);
      float e[8];
      #pragma unroll
      for (int j=0;j<8;++j) e[j] = __expf(s_trans[row*T_SZ + 8*g + j]);
      int* dst = I ? a1i : a0i;
      #pragma unroll
      for (int p=0;p<4;++p) dst[p] = pack_trunc(e[2*p], e[2*p+1]);
    }
    A0f = frag_of(a0i); A1f = frag_of(a1i);
  }

  // ---- B-frags = identity (both chains)
  int b0a[4], b1a[4], b0b[4], b1b[4];
  #pragma unroll
  for (int p=0;p<4;++p){
    int s0 = 8*g + 2*p, s1 = s0+1;
    unsigned lo = (s0==c16)?0x3f80u:0u, hi = (s1==c16)?0x3f80u:0u;
    b0a[p] = (int)(lo | (hi<<16));  b0b[p] = b0a[p];
    lo = (s0==16+c16)?0x3f80u:0u; hi = (s1==16+c16)?0x3f80u:0u;
    b1a[p] = (int)(lo | (hi<<16));  b1b[p] = b1a[p];
  }

  const long fbase = ((long)b * L_SZ) * T_SZ;
  const int  mbA = b*L_SZ + l0A;
  const int  mbB = b*L_SZ + l0B;

  float mA = mask[mbA + lane];
  float mB = mask[mbB + lane];
  int   tA = tgt [mbA + lane];
  int   tB = tgt [mbB + lane];
  int   tpA = (l0A + lane == 0) ? START_IDX : tgt[mbA + lane - 1];
  int   tpB = tgt[mbB + lane - 1];

  float emA = efeats[fbase + (long)(l0A+lane)*T_SZ + tA];
  float emB = efeats[fbase + (long)(l0B+lane)*T_SZ + tB];
  float gl = ((mA > 0.f) ? (s_trans[tA*T_SZ + tpA] + emA) : 0.f)
           + ((mB > 0.f) ? (s_trans[tB*T_SZ + tpB] + emB) : 0.f);
  float ml = mA + mB;
  #pragma unroll
  for (int off=32; off>0; off>>=1){ gl += __shfl_xor(gl, off, 64); ml += __shfl_xor(ml, off, 64); }

  unsigned long long mba = __ballot(mA > 0.f);
  unsigned long long mbb = __ballot(mB > 0.f);

  const float* fptA = efeats + fbase + (long)l0A*T_SZ;
  const float* fptB = efeats + fbase + (long)l0B*T_SZ;
  float* s_dwA = &s_d[w][0];
  float* s_dwB = &s_d[w][128];

  // prefetch pairs 1..4; stage pair 0 (both chains)
  float fqa[4], fqb[4];
  #pragma unroll
  for (int i=1; i<=4; ++i){ fqa[i&3] = fptA[i*64 + lane]; fqb[i&3] = fptB[i*64 + lane]; }
  s_dwA[lane] = __expf(fptA[lane] - SCALE_LN);
  s_dwB[lane] = __expf(fptB[lane] - SCALE_LN);

  if ((mba & mbb) == ~0ull){
    // ================= HOT: staggered dual-chain pipeline =================
    // d regs for current pair (chain A/B, h=0 and h=1)
    float4 dA0,dA1,dA2,dA3, dB0,dB1,dB2,dB3;
    {
      const float4* va = (const float4*)(s_dwA);
      const float4* vb = (const float4*)(s_dwB);
      dA0 = va[gq]; dA1 = va[gq+1]; dA2 = va[8+gq]; dA3 = va[8+gq+1];
      dB0 = vb[gq]; dB1 = vb[gq+1]; dB2 = vb[8+gq]; dB3 = vb[8+gq+1];
    }
    f32x4 cA00,cA01,cA10,cA11, cB00,cB01,cB10,cB11;

    // prologue: chain A step 0 (guarded variant; next read is only one region away)
    mfma4(A0f, A1f, frag_of(b0a), frag_of(b1a), cA00,cA01,cA10,cA11);
    __builtin_amdgcn_sched_barrier(0);

    #pragma unroll 4
    for (int p=0; p<NPAIR; ++p){
      const int nb = ((p+1)&1)*64;
      int np = p+5; np = (np > NPAIR-1) ? (NPAIR-1) : np;

      // R0: chain B MFMA, step 2p
      mfma4v(A0f, A1f, frag_of(b0b), frag_of(b1b), cB00,cB01,cB10,cB11);
      __builtin_amdgcn_sched_barrier(0);

      // R1: pack chain A step 2p + chain A exp staging for pair p+1
      PACKQ(cA00,cA01,cA10,cA11, dA0,dA1, b0a,b1a);
      s_dwA[nb + lane] = __expf(fqa[(p+1)&3] - SCALE_LN);
      fqa[(p+1)&3] = fptA[np*64 + lane];
      __builtin_amdgcn_sched_barrier(0);

      // R2: chain A MFMA, step 2p+1
      mfma4v(A0f, A1f, frag_of(b0a), frag_of(b1a), cA00,cA01,cA10,cA11);
      __builtin_amdgcn_sched_barrier(0);

      // R3: pack chain B step 2p + chain B exp staging for pair p+1
      PACKQ(cB00,cB01,cB10,cB11, dB0,dB1, b0b,b1b);
      s_dwB[nb + lane] = __expf(fqb[(p+1)&3] - SCALE_LN);
      fqb[(p+1)&3] = fptB[np*64 + lane];
      __builtin_amdgcn_sched_barrier(0);

      // R4: chain B MFMA, step 2p+1
      mfma4v(A0f, A1f, frag_of(b0b), frag_of(b1b), cB00,cB01,cB10,cB11);
      __builtin_amdgcn_sched_barrier(0);

      // R5: pack chain A step 2p+1 + prefetch next-pair dA (from buf just written in R1)
      PACKQ(cA00,cA01,cA10,cA11, dA2,dA3, b0a,b1a);
      {
        const float4* va = (const float4*)(s_dwA + nb);
        dA0 = va[gq]; dA1 = va[gq+1]; dA2 = va[8+gq]; dA3 = va[8+gq+1];
      }
      __builtin_amdgcn_sched_barrier(0);

      // R6: chain A MFMA, step 2p+2 (at p=31 this is a discarded dummy; b frags unharmed)
      mfma4v(A0f, A1f, frag_of(b0a), frag_of(b1a), cA00,cA01,cA10,cA11);
      __builtin_amdgcn_sched_barrier(0);

      // R7: pack chain B step 2p+1 + prefetch next-pair dB
      PACKQ(cB00,cB01,cB10,cB11, dB2,dB3, b0b,b1b);
      {
        const float4* vb = (const float4*)(s_dwB + nb);
        dB0 = vb[gq]; dB1 = vb[gq+1]; dB2 = vb[8+gq]; dB3 = vb[8+gq+1];
      }
      __builtin_amdgcn_sched_barrier(0);
    }
    // final matrices: b0a/b1a = chain A after step 63 (R5@p=31),
    //                b0b/b1b = chain B after step 63 (R7@p=31)
  } else {
    // ================= COLD: arbitrary mask (batched, r3-verified) =================
    for (int p=0; p<NPAIR; ++p){
      s_dwA[((p+1)&1)*64 + lane] = __expf(fqa[(p+1)&3] - SCALE_LN);
      s_dwB[((p+1)&1)*64 + lane] = __expf(fqb[(p+1)&3] - SCALE_LN);
      int np = p+5; if (np > NPAIR-1) np = NPAIR-1;
      fqa[(p+1)&3] = fptA[np*64 + lane];
      fqb[(p+1)&3] = fptB[np*64 + lane];
      const float* dbA = &s_dwA[(p&1)*64];
      const float* dbB = &s_dwB[(p&1)*64];
      #pragma unroll
      for (int h=0; h<2; ++h){
        int t = 2*p + h;
        f32x4 cA00,cA01,cA10,cA11, cB00,cB01,cB10,cB11;
        mfma8(A0f, A1f, frag_of(b0a), frag_of(b1a), frag_of(b0b), frag_of(b1b),
              cA00,cA01,cA10,cA11, cB00,cB01,cB10,cB11);

        if ((mba >> t) & 1ull){
          const float4* dvA = (const float4*)(dbA + h*32);
          float4 dl = dvA[2*g], dh2 = dvA[2*g+1];
          float f0=dl.x, f1=dl.y, f2=dl.z, f3=dl.w;
          float f4=dh2.x, f5=dh2.y, f6=dh2.z, f7=dh2.w;
          cA00[0]*=f0; cA00[1]*=f1; cA00[2]*=f2; cA00[3]*=f3;
          cA01[0]*=f0; cA01[1]*=f1; cA01[2]*=f2; cA01[3]*=f3;
          cA10[0]*=f4; cA10[1]*=f5; cA10[2]*=f6; cA10[3]*=f7;
          cA11[0]*=f4; cA11[1]*=f5; cA11[2]*=f6; cA11[3]*=f7;
          b0a[0]=pack_trunc(cA00[0],cA00[1]); b0a[1]=pack_trunc(cA00[2],cA00[3]);
          b0a[2]=pack_trunc(cA10[0],cA10[1]); b0a[3]=pack_trunc(cA10[2],cA10[3]);
          b1a[0]=pack_trunc(cA01[0],cA01[1]); b1a[1]=pack_trunc(cA01[2],cA01[3]);
          b1a[2]=pack_trunc(cA11[0],cA11[1]); b1a[3]=pack_trunc(cA11[2],cA11[3]);
        }
        if ((mbb >> t) & 1ull){
          const float4* dvB = (const float4*)(dbB + h*32);
          float4 dl = dvB[2*g], dh2 = dvB[2*g+1];
          float f0=dl.x, f1=dl.y, f2=dl.z, f3=dl.w;
          float f4=dh2.x, f5=dh2.y, f6=dh2.z, f7=dh2.w;
          cB00[0]*=f0; cB00[1]*=f1; cB00[2]*=f2; cB00[3]*=f3;
          cB01[0]*=f0; cB01[1]*=f1; cB01[2]*=f2; cB01[3]*=f3;
          cB10[0]*=f4; cB10[1]*=f5; cB10[2]*=f6; cB10[3]*=f7;
          cB11[0]*=f4; cB11[1]*=f5; cB11[2]*=f6; cB11[3]*=f7;
          b0b[0]=pack_trunc(cB00[0],cB00[1]); b0b[1]=pack_trunc(cB00[2],cB00[3]);
          b0b[2]=pack_trunc(cB10[0],cB10[1]); b0b[3]=pack_trunc(cB10[2],cB10[3]);
          b1b[0]=pack_trunc(cB01[0],cB01[1]); b1b[1]=pack_trunc(cB01[2],cB01[3]);
          b1b[2]=pack_trunc(cB11[0],cB11[1]); b1b[3]=pack_trunc(cB11[2],cB11[3]);
        }
      }
    }
  }

  // ---- write chunk matrices to tree slots (chain A -> slot 2w in R layout, chain B -> slot 2w+1 in T layout)
  {
    unsigned short* S = &s_tree[2*w][0];
    #pragma unroll
    for (int p=0;p<4;++p){
      int s = 8*g + 2*p;
      *(int*)&S[c16*T_SZ + s]      = b0a[p];
      *(int*)&S[(16+c16)*T_SZ + s] = b1a[p];
    }
    unsigned short* St = &s_tree[2*w+1][0];
    #pragma unroll
    for (int p=0;p<4;++p){
      int s = 8*g + 2*p;
      St[s*T_SZ + c16]          = (unsigned short)(b0b[p] & 0xffff);
      St[(s+1)*T_SZ + c16]      = (unsigned short)(((unsigned)b0b[p])>>16);
      St[s*T_SZ + 16 + c16]     = (unsigned short)(b1b[p] & 0xffff);
      St[(s+1)*T_SZ + 16 + c16] = (unsigned short)(((unsigned)b1b[p])>>16);
    }
  }
  if (lane==0){
    s_et[2*w]   = 6 * __popcll(mba);
    s_et[2*w+1] = 6 * __popcll(mbb);
    s_gd[w] = gl; s_ml[w] = ml;
  }
  __syncthreads();

  // ---- tree: 8 -> 1 (4 waves at level 1)
  {
    int e = mat_prod(&s_tree[2*w][0], &s_tree[2*w+1][0], &s_tree[2*w][0], (w&1)!=0, lane);
    if (lane==0) s_et[2*w] = s_et[2*w] + s_et[2*w+1] + e;
  }
  __syncthreads();
  if (w < 2){
    int e = mat_prod(&s_tree[4*w][0], &s_tree[4*w+2][0], &s_tree[4*w][0], (w&1)!=0, lane);
    if (lane==0) s_et[4*w] = s_et[4*w] + s_et[4*w+2] + e;
  }
  __syncthreads();
  if (w == 0){
    int e = mat_prod(&s_tree[0][0], &s_tree[4][0], &s_tree[0][0], false, lane);
    if (lane==0) s_et[0] = s_et[0] + s_et[4] + e;
  }
  __syncthreads();

  // ---- export block matrix (R layout) + scalars
  const int bid = blockIdx.x;
  ((int*)(wsM + (long)bid*(T_SZ*T_SZ)))[tid]       = ((const int*)&s_tree[0][0])[tid];
  ((int*)(wsM + (long)bid*(T_SZ*T_SZ)))[tid + 256] = ((const int*)&s_tree[0][0])[tid + 256];
  if (tid == 0){
    wsE[bid] = s_et[0];
    float gs=0.f, ls=0.f;
    #pragma unroll
    for (int i=0;i<4;++i){ gs += s_gd[i]; ls += s_ml[i]; }
    wsG[bid] = gs; wsL[bid] = ls;
  }
}

// ===================== kernel 2: combine 4 block-matrices per sequence =====================
__global__ __launch_bounds__(64) void crf_combine_kernel(
    const unsigned short* __restrict__ wsM, const int* __restrict__ wsE,
    const float* __restrict__ wsG, const float* __restrict__ wsL,
    const int* __restrict__ tgt, const float* __restrict__ trans,
    float* __restrict__ out)
{
  __shared__ unsigned short sM[NMAT_SEQ*T_SZ*T_SZ];   // 8 KiB = NMAT_SEQ*128 uint4
  __shared__ float s_v[T_SZ];

  const int tid = threadIdx.x;
  const int b   = blockIdx.x;

  const uint4* src = (const uint4*)(wsM + (long)b*NMAT_SEQ*T_SZ*T_SZ);
  #pragma unroll
  for (int i=0;i<NMAT_SEQ*2;++i) ((uint4*)sM)[tid + i*64] = src[tid + i*64];
  __syncthreads();

  const int s = tid & 31;
  float v = (s==START_IDX)?1.f:0.f;
  int E = 0;
  #pragma unroll
  for (int j=0; j<NMAT_SEQ; ++j){
    if (tid < 32) s_v[s] = v;
    __syncthreads();
    const unsigned short* M = &sM[j*T_SZ*T_SZ];
    float u = 0.f;
    #pragma unroll 8
    for (int x=0; x<T_SZ; ++x){
      float mv = uaf(((unsigned)M[x*T_SZ + s])<<16);
      u = fmaf(mv, s_v[x], u);
    }
    unsigned ub = (unsigned)__builtin_amdgcn_readfirstlane((int)fau(u));
    int eu = (int)((ub>>23)&255u)-127;
    E += wsE[b*NMAT_SEQ + j] + eu;
    v = u * uaf((unsigned)(127-eu)<<23);
    __syncthreads();
  }
  float term = v * __expf(trans[STOP_IDX*T_SZ + s]);
  #pragma unroll
  for (int off=16; off>0; off>>=1) term += __shfl_xor(term, off, 32);
  float fwd = (float)E * 0.69314718055994530942f + __logf(term);

  if (tid == 0){
    float gp = 0.f, lp = 0.f;
    #pragma unroll
    for (int j=0;j<NMAT_SEQ;++j){ gp += wsG[b*NMAT_SEQ+j]; lp += wsL[b*NMAT_SEQ+j]; }
    int len = (int)lp;
    int last_tag = (len==0)? START_IDX : tgt[b*L_SZ + len-1];
    float goldT = gp + trans[STOP_IDX*T_SZ + last_tag];
    atomicAdd(out, (fwd - goldT) * (1.0f/B_SZ));
  }
}

// ===================== fallback: round-1 single kernel (no workspace) =====================
__global__ __launch_bounds__(1024) void crf_loss_kernel(
    const float* __restrict__ efeats, const float* __restrict__ mask,
    const int* __restrict__ tgt, const float* __restrict__ trans,
    float* __restrict__ out)
{
  __shared__ float s_trans[T_SZ*T_SZ];
  __shared__ float s_d[FB_NCH][T_SZ];
  __shared__ unsigned short s_M[FB_NCH][T_SZ*T_SZ];
  __shared__ int   s_es[FB_NCH];
  __shared__ float s_gd[FB_NCH];
  __shared__ float s_mlv[FB_NCH];

  const int tid  = threadIdx.x;
  const int b    = blockIdx.x;
  const int w    = tid >> 6;
  const int lane = tid & 63;
  const int g    = lane >> 4;
  const int c16  = lane & 15;
  const int i32  = lane & 31;

  s_trans[tid] = trans[tid];
  __syncthreads();

  int a0[4], a1[4];
  #pragma unroll
  for (int I=0; I<2; ++I){
    int row = 8*(c16>>2) + 4*I + (c16&3);
    float e[8];
    #pragma unroll
    for (int j=0;j<8;++j) e[j] = __expf(s_trans[row*T_SZ + 8*g + j]);
    int* dst = I ? a1 : a0;
    #pragma unroll
    for (int p=0;p<4;++p) dst[p] = pack_trunc(e[2*p], e[2*p+1]);
  }

  int b0[4], b1[4];
  #pragma unroll
  for (int p=0;p<4;++p){
    int s0 = 8*g + 2*p, s1 = s0+1;
    unsigned lo = (s0==c16)?0x3f80u:0u, hi = (s1==c16)?0x3f80u:0u;
    b0[p] = (int)(lo | (hi<<16));
    lo = (s0==16+c16)?0x3f80u:0u; hi = (s1==16+c16)?0x3f80u:0u;
    b1[p] = (int)(lo | (hi<<16));
  }

  const int l0 = w * FB_CLEN;
  const long fbase = ((long)b * L_SZ) * T_SZ;

  float fqv[4];
  #pragma unroll
  for (int i=0;i<4;++i) fqv[i] = efeats[fbase + (long)(l0+i)*T_SZ + i32];

  int   tA = tgt [b*L_SZ + l0 + lane];
  int   tB = tgt [b*L_SZ + l0 + 64 + lane];
  float mA = mask[b*L_SZ + l0 + lane];
  float mB = mask[b*L_SZ + l0 + 64 + lane];
  int prev = (l0==0) ? START_IDX : tgt[b*L_SZ + l0 - 1];

  int esum = 0;
  float gold = 0.f, mlen = 0.f;
  const f32x4 zf = {0.f,0.f,0.f,0.f};

  #pragma unroll 4
  for (int t=0; t<FB_CLEN; ++t){
    float fcur = fqv[t&3];
    int lpf = l0 + t + 4; lpf = (lpf < L_SZ) ? lpf : (L_SZ-1);
    fqv[t&3] = efeats[fbase + (long)lpf*T_SZ + i32];

    float mk  = uaf((unsigned)__builtin_amdgcn_readlane((int)fau((t<64)?mA:mB), t&63));
    int   cur = __builtin_amdgcn_readlane((t<64)?tA:tB, t&63);
    mlen += mk;

    if (mk > 0.f){
      if (lane < 32) s_d[w][lane] = __expf(fcur);

      f32x4 c00 = __builtin_amdgcn_mfma_f32_16x16x32_bf16(frag_of(a0), frag_of(b0), zf, 0,0,0);
      f32x4 c01 = __builtin_amdgcn_mfma_f32_16x16x32_bf16(frag_of(a0), frag_of(b1), zf, 0,0,0);
      f32x4 c10 = __builtin_amdgcn_mfma_f32_16x16x32_bf16(frag_of(a1), frag_of(b0), zf, 0,0,0);
      f32x4 c11 = __builtin_amdgcn_mfma_f32_16x16x32_bf16(frag_of(a1), frag_of(b1), zf, 0,0,0);

      const float4* dv = (const float4*)(&s_d[w][0]);
      float4 dl = dv[2*g], dh = dv[2*g+1];
      float f0=dl.x, f1=dl.y, f2=dl.z, f3=dl.w;
      float f4=dh.x, f5=dh.y, f6=dh.z, f7=dh.w;

      float m00 = c00[0]*f0;
      unsigned mb = (unsigned)__builtin_amdgcn_readfirstlane((int)fau(m00));
      int e = (int)((mb>>23)&255u) - 127;
      esum += e;
      float r = uaf((unsigned)(127-e)<<23);
      f0*=r; f1*=r; f2*=r; f3*=r; f4*=r; f5*=r; f6*=r; f7*=r;

      c00[0]*=f0; c00[1]*=f1; c00[2]*=f2; c00[3]*=f3;
      c01[0]*=f0; c01[1]*=f1; c01[2]*=f2; c01[3]*=f3;
      c10[0]*=f4; c10[1]*=f5; c10[2]*=f6; c10[3]*=f7;
      c11[0]*=f4; c11[1]*=f5; c11[2]*=f6; c11[3]*=f7;

      b0[0]=pack_trunc(c00[0],c00[1]); b0[1]=pack_trunc(c00[2],c00[3]);
      b0[2]=pack_trunc(c10[0],c10[1]); b0[3]=pack_trunc(c10[2],c10[3]);
      b1[0]=pack_trunc(c01[0],c01[1]); b1[1]=pack_trunc(c01[2],c01[3]);
      b1[2]=pack_trunc(c11[0],c11[1]); b1[3]=pack_trunc(c11[2],c11[3]);

      float tp   = s_trans[cur*T_SZ + prev];
      float emit = uaf((unsigned)__builtin_amdgcn_readlane((int)fau(fcur), cur));
      gold += tp + emit;
    }
    prev = cur;
  }

  #pragma unroll
  for (int p=0;p<4;++p){
    int s = 8*g + 2*p;
    *(int*)((char*)(&s_M[w][0]) + (((long)(c16   )*T_SZ + s) * 2)) = b0[p];
    *(int*)((char*)(&s_M[w][0]) + (((long)(16+c16)*T_SZ + s) * 2)) = b1[p];
  }
  if (lane==0){ s_es[w]=esum; s_gd[w]=gold; s_mlv[w]=mlen; }
  __syncthreads();

  if (w==0){
    int s = i32;
    float v = (s==START_IDX)?1.f:0.f;
    int E = 0;
    for (int c=0;c<FB_NCH;++c){
      float u=0.f;
      #pragma unroll 8
      for (int k=0;k<T_SZ;++k){
        float mv = uaf(((unsigned)s_M[c][k*T_SZ + s])<<16);
        float vk = uaf((unsigned)__builtin_amdgcn_readlane((int)fau(v), k));
        u = fmaf(mv, vk, u);
      }
      unsigned ub = (unsigned)__builtin_amdgcn_readfirstlane((int)fau(u));
      int eu = (int)((ub>>23)&255u)-127;
      E += s_es[c] + eu;
      v = u * uaf((unsigned)(127-eu)<<23);
    }
    float term = v * __expf(s_trans[STOP_IDX*T_SZ + s]);
    #pragma unroll
    for (int off=16; off>0; off>>=1) term += __shfl_xor(term, off, 32);
    float fwd = (float)E * 0.69314718055994530942f + __logf(term);

    float gp = (s<FB_NCH)? s_gd[s] : 0.f;
    float lp = (s<FB_NCH)? s_mlv[s] : 0.f;
    #pragma unroll
    for (int off=16; off>0; off>>=1){ gp += __shfl_xor(gp, off, 32); lp += __shfl_xor(lp, off, 32); }
    int len = (int)lp;
    int last_tag = (len==0)? START_IDX : tgt[b*L_SZ + (len-1)];
    float goldT = gp + s_trans[STOP_IDX*T_SZ + last_tag];
    if (tid==0) atomicAdd(out, (fwd - goldT) * (1.0f/B_SZ));
  }
}

extern "C" void kernel_launch(void* const* d_in, const int* in_sizes, int n_in,
                              void* d_out, int out_size, void* d_ws, size_t ws_size,
                              hipStream_t stream)
{
  const float* efeats = (const float*)d_in[0];
  const float* mask   = (const float*)d_in[1];
  const int*   tgt    = (const int*)d_in[2];
  const float* trans  = (const float*)d_in[3];
  float* out = (float*)d_out;

  const size_t needM = (size_t)NBLK_TOT * T_SZ * T_SZ * 2;   // 2 MiB
  const size_t need  = needM + (size_t)NBLK_TOT * 12;

  if (ws_size >= need){
    unsigned short* wsM = (unsigned short*)d_ws;
    char* p = (char*)d_ws + needM;
    int*   wsE = (int*)p;
    float* wsG = (float*)(p + (size_t)NBLK_TOT*4);
    float* wsL = (float*)(p + (size_t)NBLK_TOT*8);
    crf_chunk_kernel<<<dim3(NBLK_TOT), dim3(256), 0, stream>>>(
        efeats, mask, tgt, trans, wsM, wsE, wsG, wsL, out);
    crf_combine_kernel<<<dim3(B_SZ), dim3(64), 0, stream>>>(
        wsM, wsE, wsG, wsL, tgt, trans, out);
  } else {
    zero_kernel<<<dim3(1), dim3(64), 0, stream>>>(out);
    crf_loss_kernel<<<dim3(B_SZ), dim3(1024), 0, stream>>>(efeats, mask, tgt, trans, out);
  }
}